// Round 2
// baseline (326.268 us; speedup 1.0000x reference)
//
#include <hip/hip_runtime.h>

// FastFood layer: out = (1/sqrt(D)) * [cos(w), sin(w)] + bias
//   w = (1/sqrt(D)) * S ⊙ FWHT( G ⊙ Perm( FWHT( B ⊙ x ) ) )
//
// Stack-per-wave design: block = 1 row (256 thr), wave w = stack w.
//
// The FWHT never leaves registers. Element-index mapping is fixed for the
// whole transform (A-mapping):
//   e[1:0] = reg[1:0], e[9:8] = reg[3:2], e[7:2] = lane[5:0]
// Stages on e0,e1,e8,e9: in-register add/sub pairs (STAGE_BIT).
// Stages on e2..e6: cross-lane XOR via ds_swizzle BitMode (masks 1,2,4,8,16),
//   butterfly as v = fma(sign, v, partner)  (sign = -1 on upper lane).
// Stage on e7 (lane^32, crosses the 32-lane swizzle group): __shfl_xor.
// This deletes all LDS remap round-trips (write -> lgkmcnt drain -> read),
// all wave_barriers between remaps, and all XOR-swizzle address math. The
// only LDS use left is the unavoidable random-permutation gather (linear
// layout, wave-private 4 KB).

#define FF_D 1024
#define FF_STACK 4
#define FF_NT 256

// BitMode ds_swizzle: offset = (xor<<10) | (or<<5) | and, and=0x1F, or=0.
#define SWZF(vf, OFF) \
    __int_as_float(__builtin_amdgcn_ds_swizzle(__float_as_int(vf), (OFF)))

// in-register butterfly on reg-bit m
#define STAGE_BIT(vv, m) { \
    _Pragma("unroll") \
    for (int i_ = 0; i_ < 16; ++i_) \
        if (!(i_ & (m))) { \
            float s_ = vv[i_] + vv[i_ | (m)]; \
            float d_ = vv[i_] - vv[i_ | (m)]; \
            vv[i_] = s_; vv[i_ | (m)] = d_; \
        } \
}

// cross-lane butterfly via ds_swizzle with literal BitMode offset OFF;
// sgn = -1 on the lane whose stage bit is set (v = sgn*v + partner).
#define STAGE_SWZ(vv, OFF, sgn) { \
    float p_[16]; \
    _Pragma("unroll") \
    for (int i_ = 0; i_ < 16; ++i_) p_[i_] = SWZF(vv[i_], OFF); \
    _Pragma("unroll") \
    for (int i_ = 0; i_ < 16; ++i_) vv[i_] = __builtin_fmaf(sgn, vv[i_], p_[i_]); \
}

// cross-lane butterfly on lane-xor 32 (crosses the 32-lane swizzle group)
#define STAGE_X32(vv, sgn) { \
    float p_[16]; \
    _Pragma("unroll") \
    for (int i_ = 0; i_ < 16; ++i_) p_[i_] = __shfl_xor(vv[i_], 32, 64); \
    _Pragma("unroll") \
    for (int i_ = 0; i_ < 16; ++i_) vv[i_] = __builtin_fmaf(sgn, vv[i_], p_[i_]); \
}

// full 1024-point FWHT, all in registers (stage order is free: stages commute)
#define FWHT10(vv) { \
    STAGE_BIT(vv, 1) STAGE_BIT(vv, 2) STAGE_BIT(vv, 4) STAGE_BIT(vv, 8) \
    STAGE_SWZ(vv, 0x041F, sg1)  /* lane^1  */ \
    STAGE_SWZ(vv, 0x081F, sg2)  /* lane^2  */ \
    STAGE_SWZ(vv, 0x101F, sg4)  /* lane^4  */ \
    STAGE_SWZ(vv, 0x201F, sg8)  /* lane^8  */ \
    STAGE_SWZ(vv, 0x401F, sg16) /* lane^16 */ \
    STAGE_X32(vv, sg32)         /* lane^32 */ \
}

__global__ __launch_bounds__(FF_NT) void fastfood_kernel(
    const float* __restrict__ x,
    const float* __restrict__ Bs,
    const float* __restrict__ G,
    const float* __restrict__ S,
    const float* __restrict__ bias,
    const int*   __restrict__ P,
    float* __restrict__ out)
{
    __shared__ float lds[FF_STACK * FF_D];
    const int lane = threadIdx.x & 63;
    const int s    = threadIdx.x >> 6;      // stack handled by this wave
    const int row  = blockIdx.x;
    const int sb   = s << 10;
    float* wl = lds + sb;                   // wave-private 4 KB, linear layout

    // butterfly signs per lane-stage: -1 where the lane's stage bit is set
    const float sg1  = (lane & 1)  ? -1.0f : 1.0f;
    const float sg2  = (lane & 2)  ? -1.0f : 1.0f;
    const float sg4  = (lane & 4)  ? -1.0f : 1.0f;
    const float sg8  = (lane & 8)  ? -1.0f : 1.0f;
    const float sg16 = (lane & 16) ? -1.0f : 1.0f;
    const float sg32 = (lane & 32) ? -1.0f : 1.0f;

    const float kout = 0.03125f;                      // 1/sqrt(1024)
    const float karg = 0.03125f * 0.15915494309f;     // /(2*pi): revolutions

    float v[16];

    // Load x row (A mapping), fused with diag B.
    #pragma unroll
    for (int q = 0; q < 4; ++q) {
        const float4 t  = *(const float4*)&x[((long long)row << 10) + (q << 8) + (lane << 2)];
        const float4 b4 = *(const float4*)&Bs[sb + (q << 8) + (lane << 2)];
        v[4*q+0] = t.x * b4.x; v[4*q+1] = t.y * b4.y;
        v[4*q+2] = t.z * b4.z; v[4*q+3] = t.w * b4.w;
    }

    // ---------- FWHT #1 (fully in-register) ----------
    FWHT10(v)

    // ---------- permutation gather + diag G ----------
    // park the row linearly in wave-private LDS ...
    #pragma unroll
    for (int q = 0; q < 4; ++q)
        *(float4*)&wl[(q << 8) | (lane << 2)] =
            make_float4(v[4*q], v[4*q+1], v[4*q+2], v[4*q+3]);
    __builtin_amdgcn_wave_barrier();
    // ... and gather back through P (per-stack indices), fused with diag G
    #pragma unroll
    for (int q = 0; q < 4; ++q) {
        const int jb = sb + (q << 8) + (lane << 2);
        const int4   p4 = *(const int4*)&P[jb];
        const float4 g4 = *(const float4*)&G[jb];
        v[4*q+0] = wl[p4.x & (FF_D - 1)] * g4.x;
        v[4*q+1] = wl[p4.y & (FF_D - 1)] * g4.y;
        v[4*q+2] = wl[p4.z & (FF_D - 1)] * g4.z;
        v[4*q+3] = wl[p4.w & (FF_D - 1)] * g4.w;
    }

    // ---------- FWHT #2 (fully in-register) ----------
    FWHT10(v)

    // ---------- epilogue (A mapping): scale, sincos, store ----------
    // per q, the wave's 64 float4 stores cover one contiguous 1 KB segment
    const long long obase = ((long long)row << 13);   // row * 8192
    #pragma unroll
    for (int q = 0; q < 4; ++q) {
        const int j = sb + (q << 8) + (lane << 2);
        const float4 s4  = *(const float4*)&S[j];
        const float4 bc4 = *(const float4*)&bias[j];
        const float4 bs4 = *(const float4*)&bias[FF_STACK * FF_D + j];
        float4 oc, os;
        {
            const float tr = __builtin_amdgcn_fractf(v[4*q+0] * (s4.x * karg));
            oc.x = __builtin_amdgcn_cosf(tr) * kout + bc4.x;
            os.x = __builtin_amdgcn_sinf(tr) * kout + bs4.x;
        }
        {
            const float tr = __builtin_amdgcn_fractf(v[4*q+1] * (s4.y * karg));
            oc.y = __builtin_amdgcn_cosf(tr) * kout + bc4.y;
            os.y = __builtin_amdgcn_sinf(tr) * kout + bs4.y;
        }
        {
            const float tr = __builtin_amdgcn_fractf(v[4*q+2] * (s4.z * karg));
            oc.z = __builtin_amdgcn_cosf(tr) * kout + bc4.z;
            os.z = __builtin_amdgcn_sinf(tr) * kout + bs4.z;
        }
        {
            const float tr = __builtin_amdgcn_fractf(v[4*q+3] * (s4.w * karg));
            oc.w = __builtin_amdgcn_cosf(tr) * kout + bc4.w;
            os.w = __builtin_amdgcn_sinf(tr) * kout + bs4.w;
        }
        *(float4*)&out[obase + j] = oc;
        *(float4*)&out[obase + FF_STACK * FF_D + j] = os;
    }
}

extern "C" void kernel_launch(void* const* d_in, const int* in_sizes, int n_in,
                              void* d_out, int out_size, void* d_ws, size_t ws_size,
                              hipStream_t stream) {
    // setup_inputs order: x, B, G, S, bias, H, P   (H unused: FWHT instead)
    const float* x    = (const float*)d_in[0];
    const float* B    = (const float*)d_in[1];
    const float* G    = (const float*)d_in[2];
    const float* S    = (const float*)d_in[3];
    const float* bias = (const float*)d_in[4];
    const int*   P    = (const int*)d_in[6];
    float* out = (float*)d_out;

    const int n_rows = in_sizes[0] / FF_D;   // 8192
    fastfood_kernel<<<n_rows, FF_NT, 0, stream>>>(x, B, G, S, bias, P, out);
}

// Round 3
// 305.330 us; speedup vs baseline: 1.0686x; 1.0686x over previous
//
#include <hip/hip_runtime.h>

// FastFood layer: out = (1/sqrt(D)) * [cos(w), sin(w)] + bias
//   w = (1/sqrt(D)) * S ⊙ FWHT( G ⊙ Perm( FWHT( B ⊙ x ) ) )
//
// Two-rows-per-block design: block = 2 rows (256 thr), wave w = stack w for
// BOTH rows. Each wave carries two independent dependency chains (v0, v1),
// interleaved op-by-op, so every cross-lane / LDS / global-load stall has
// a second chain to execute under it. B/P/G/S/bias loads and sign setup are
// shared across the two rows.
//
// FWHT is fully in-register (A-mapping, fixed):
//   e[1:0] = reg[1:0], e[9:8] = reg[3:2], e[7:2] = lane[5:0]
// Stages e0,e1,e8,e9: in-register add/sub. Stages e2..e6: ds_swizzle
// BitMode XOR (masks 1,2,4,8,16), butterfly v = fma(sign, v, partner).
// Stage e7: __shfl_xor(v, 32). Only remaining LDS use: the random
// permutation gather (linear wave-private 4 KB per row).

#define FF_D 1024
#define FF_STACK 4
#define FF_NT 256

// BitMode ds_swizzle: offset = (xor<<10) | (or<<5) | and, and=0x1F, or=0.
#define SWZF(vf, OFF) \
    __int_as_float(__builtin_amdgcn_ds_swizzle(__float_as_int(vf), (OFF)))

// in-register butterfly on reg-bit m, both rows
#define STAGE_BIT2(aa, bb, m) { \
    _Pragma("unroll") \
    for (int i_ = 0; i_ < 16; ++i_) \
        if (!(i_ & (m))) { \
            float sa_ = aa[i_] + aa[i_ | (m)]; \
            float da_ = aa[i_] - aa[i_ | (m)]; \
            aa[i_] = sa_; aa[i_ | (m)] = da_; \
            float sb_ = bb[i_] + bb[i_ | (m)]; \
            float db_ = bb[i_] - bb[i_ | (m)]; \
            bb[i_] = sb_; bb[i_ | (m)] = db_; \
        } \
}

// cross-lane butterfly via ds_swizzle (literal BitMode offset OFF), both rows;
// all 32 swizzles issued before any consumer -> deep lgkmcnt pipelining.
#define STAGE_SWZ2(aa, bb, OFF, sgn) { \
    float pa_[16], pb_[16]; \
    _Pragma("unroll") \
    for (int i_ = 0; i_ < 16; ++i_) pa_[i_] = SWZF(aa[i_], OFF); \
    _Pragma("unroll") \
    for (int i_ = 0; i_ < 16; ++i_) pb_[i_] = SWZF(bb[i_], OFF); \
    _Pragma("unroll") \
    for (int i_ = 0; i_ < 16; ++i_) aa[i_] = __builtin_fmaf(sgn, aa[i_], pa_[i_]); \
    _Pragma("unroll") \
    for (int i_ = 0; i_ < 16; ++i_) bb[i_] = __builtin_fmaf(sgn, bb[i_], pb_[i_]); \
}

// cross-lane butterfly on lane-xor 32, both rows
#define STAGE_X32_2(aa, bb, sgn) { \
    float pa_[16], pb_[16]; \
    _Pragma("unroll") \
    for (int i_ = 0; i_ < 16; ++i_) pa_[i_] = __shfl_xor(aa[i_], 32, 64); \
    _Pragma("unroll") \
    for (int i_ = 0; i_ < 16; ++i_) pb_[i_] = __shfl_xor(bb[i_], 32, 64); \
    _Pragma("unroll") \
    for (int i_ = 0; i_ < 16; ++i_) aa[i_] = __builtin_fmaf(sgn, aa[i_], pa_[i_]); \
    _Pragma("unroll") \
    for (int i_ = 0; i_ < 16; ++i_) bb[i_] = __builtin_fmaf(sgn, bb[i_], pb_[i_]); \
}

// full 1024-point FWHT on two rows, all in registers
#define FWHT10_2(aa, bb) { \
    STAGE_BIT2(aa, bb, 1) STAGE_BIT2(aa, bb, 2) \
    STAGE_BIT2(aa, bb, 4) STAGE_BIT2(aa, bb, 8) \
    STAGE_SWZ2(aa, bb, 0x041F, sg1)  /* lane^1  */ \
    STAGE_SWZ2(aa, bb, 0x081F, sg2)  /* lane^2  */ \
    STAGE_SWZ2(aa, bb, 0x101F, sg4)  /* lane^4  */ \
    STAGE_SWZ2(aa, bb, 0x201F, sg8)  /* lane^8  */ \
    STAGE_SWZ2(aa, bb, 0x401F, sg16) /* lane^16 */ \
    STAGE_X32_2(aa, bb, sg32)        /* lane^32 */ \
}

// sincos epilogue for one element
#define CS1(val, sc, bc, bs, oC, oS) { \
    const float tr_ = __builtin_amdgcn_fractf((val) * ((sc) * karg)); \
    oC = __builtin_amdgcn_cosf(tr_) * kout + (bc); \
    oS = __builtin_amdgcn_sinf(tr_) * kout + (bs); \
}

__global__ __launch_bounds__(FF_NT) void fastfood_kernel(
    const float* __restrict__ x,
    const float* __restrict__ Bs,
    const float* __restrict__ G,
    const float* __restrict__ S,
    const float* __restrict__ bias,
    const int*   __restrict__ P,
    float* __restrict__ out)
{
    __shared__ float lds[2 * FF_STACK * FF_D];   // 32 KB: [row01][stack][1024]
    const int lane = threadIdx.x & 63;
    const int s    = threadIdx.x >> 6;           // stack handled by this wave
    const int row0 = blockIdx.x << 1;
    const int sb   = s << 10;
    float* wl0 = lds + sb;                       // row0, wave-private 4 KB
    float* wl1 = lds + FF_STACK * FF_D + sb;     // row1, wave-private 4 KB

    // butterfly signs per lane-stage: -1 where the lane's stage bit is set
    const float sg1  = (lane & 1)  ? -1.0f : 1.0f;
    const float sg2  = (lane & 2)  ? -1.0f : 1.0f;
    const float sg4  = (lane & 4)  ? -1.0f : 1.0f;
    const float sg8  = (lane & 8)  ? -1.0f : 1.0f;
    const float sg16 = (lane & 16) ? -1.0f : 1.0f;
    const float sg32 = (lane & 32) ? -1.0f : 1.0f;

    const float kout = 0.03125f;                      // 1/sqrt(1024)
    const float karg = 0.03125f * 0.15915494309f;     // /(2*pi): revolutions

    float v0[16], v1[16];

    // Load both x rows (A mapping), fused with diag B (shared).
    const long long xb0 = ((long long)row0 << 10);
    #pragma unroll
    for (int q = 0; q < 4; ++q) {
        const int eo = (q << 8) + (lane << 2);
        const float4 t0 = *(const float4*)&x[xb0 + eo];
        const float4 t1 = *(const float4*)&x[xb0 + FF_D + eo];
        const float4 b4 = *(const float4*)&Bs[sb + eo];
        v0[4*q+0] = t0.x * b4.x; v0[4*q+1] = t0.y * b4.y;
        v0[4*q+2] = t0.z * b4.z; v0[4*q+3] = t0.w * b4.w;
        v1[4*q+0] = t1.x * b4.x; v1[4*q+1] = t1.y * b4.y;
        v1[4*q+2] = t1.z * b4.z; v1[4*q+3] = t1.w * b4.w;
    }

    // ---------- FWHT #1 (both rows, in-register) ----------
    FWHT10_2(v0, v1)

    // ---------- permutation gather + diag G (P/G shared across rows) ----------
    // issue P/G loads first so their latency hides under the park + barrier
    int4   p4[4];
    float4 g4[4];
    #pragma unroll
    for (int q = 0; q < 4; ++q) {
        const int jb = sb + (q << 8) + (lane << 2);
        p4[q] = *(const int4*)&P[jb];
        g4[q] = *(const float4*)&G[jb];
    }
    // park both rows linearly in wave-private LDS
    #pragma unroll
    for (int q = 0; q < 4; ++q) {
        const int eo = (q << 8) | (lane << 2);
        *(float4*)&wl0[eo] = make_float4(v0[4*q], v0[4*q+1], v0[4*q+2], v0[4*q+3]);
        *(float4*)&wl1[eo] = make_float4(v1[4*q], v1[4*q+1], v1[4*q+2], v1[4*q+3]);
    }
    __builtin_amdgcn_wave_barrier();
    // gather both rows through the same indices, fused with diag G
    #pragma unroll
    for (int q = 0; q < 4; ++q) {
        const int ix = p4[q].x & (FF_D - 1);
        const int iy = p4[q].y & (FF_D - 1);
        const int iz = p4[q].z & (FF_D - 1);
        const int iw = p4[q].w & (FF_D - 1);
        v0[4*q+0] = wl0[ix] * g4[q].x;  v1[4*q+0] = wl1[ix] * g4[q].x;
        v0[4*q+1] = wl0[iy] * g4[q].y;  v1[4*q+1] = wl1[iy] * g4[q].y;
        v0[4*q+2] = wl0[iz] * g4[q].z;  v1[4*q+2] = wl1[iz] * g4[q].z;
        v0[4*q+3] = wl0[iw] * g4[q].w;  v1[4*q+3] = wl1[iw] * g4[q].w;
    }

    // ---------- FWHT #2 (both rows, in-register) ----------
    FWHT10_2(v0, v1)

    // ---------- epilogue (A mapping): scale, sincos, store (S/bias shared) ----------
    const long long ob0 = ((long long)row0 << 13);            // row0 * 8192
    const long long ob1 = ob0 + (FF_STACK * FF_D * 2);        // row1 * 8192
    #pragma unroll
    for (int q = 0; q < 4; ++q) {
        const int j = sb + (q << 8) + (lane << 2);
        const float4 s4  = *(const float4*)&S[j];
        const float4 bc4 = *(const float4*)&bias[j];
        const float4 bs4 = *(const float4*)&bias[FF_STACK * FF_D + j];
        float4 oc0, os0, oc1, os1;
        CS1(v0[4*q+0], s4.x, bc4.x, bs4.x, oc0.x, os0.x)
        CS1(v1[4*q+0], s4.x, bc4.x, bs4.x, oc1.x, os1.x)
        CS1(v0[4*q+1], s4.y, bc4.y, bs4.y, oc0.y, os0.y)
        CS1(v1[4*q+1], s4.y, bc4.y, bs4.y, oc1.y, os1.y)
        CS1(v0[4*q+2], s4.z, bc4.z, bs4.z, oc0.z, os0.z)
        CS1(v1[4*q+2], s4.z, bc4.z, bs4.z, oc1.z, os1.z)
        CS1(v0[4*q+3], s4.w, bc4.w, bs4.w, oc0.w, os0.w)
        CS1(v1[4*q+3], s4.w, bc4.w, bs4.w, oc1.w, os1.w)
        *(float4*)&out[ob0 + j] = oc0;
        *(float4*)&out[ob0 + FF_STACK * FF_D + j] = os0;
        *(float4*)&out[ob1 + j] = oc1;
        *(float4*)&out[ob1 + FF_STACK * FF_D + j] = os1;
    }
}

extern "C" void kernel_launch(void* const* d_in, const int* in_sizes, int n_in,
                              void* d_out, int out_size, void* d_ws, size_t ws_size,
                              hipStream_t stream) {
    // setup_inputs order: x, B, G, S, bias, H, P   (H unused: FWHT instead)
    const float* x    = (const float*)d_in[0];
    const float* B    = (const float*)d_in[1];
    const float* G    = (const float*)d_in[2];
    const float* S    = (const float*)d_in[3];
    const float* bias = (const float*)d_in[4];
    const int*   P    = (const int*)d_in[6];
    float* out = (float*)d_out;

    const int n_rows = in_sizes[0] / FF_D;   // 8192
    fastfood_kernel<<<n_rows / 2, FF_NT, 0, stream>>>(x, B, G, S, bias, P, out);
}